// Round 2
// baseline (3324.283 us; speedup 1.0000x reference)
//
#include <hip/hip_runtime.h>
#include <hip/hip_bf16.h>

// Problem constants
#define BB 4
#define LL 2048
#define DM 1024
#define DI 2048          // D_INNER
#define DST 16           // D_STATE
#define DTR 64           // DT_RANK
#define ROWS (BB*LL)     // 8192

// ---------------------------------------------------------------------------
// 1. LN stats: per-row mu and rsqrt(var+eps)  -> stats[row*2 + {0,1}]
// ---------------------------------------------------------------------------
__global__ __launch_bounds__(256) void ln_stats_kernel(const float* __restrict__ x,
                                                       float* __restrict__ stats) {
    const int row = blockIdx.x;
    const int tid = threadIdx.x;
    const float4 v = ((const float4*)(x + (size_t)row * DM))[tid];
    float s  = v.x + v.y + v.z + v.w;
    float sq = v.x*v.x + v.y*v.y + v.z*v.z + v.w*v.w;
    #pragma unroll
    for (int m = 1; m < 64; m <<= 1) {
        s  += __shfl_xor(s, m);
        sq += __shfl_xor(sq, m);
    }
    __shared__ float ss[4], ssq[4];
    const int w = tid >> 6;
    if ((tid & 63) == 0) { ss[w] = s; ssq[w] = sq; }
    __syncthreads();
    if (tid == 0) {
        s  = ss[0] + ss[1] + ss[2] + ss[3];
        sq = ssq[0] + ssq[1] + ssq[2] + ssq[3];
        const float mu  = s * (1.f / DM);
        const float var = sq * (1.f / DM) - mu * mu;
        stats[row * 2 + 0] = mu;
        stats[row * 2 + 1] = rsqrtf(var + 1e-5f);
    }
}

// ---------------------------------------------------------------------------
// 2. f32 tiled GEMM: C[M,N] = A[M,K] @ B[K,N] (+ Add).  128x128 tile, BK=16,
//    256 threads, 8x8 micro-tile split 4+4.
//    LN=true: A is raw x; apply (a-mu)*rs*g+b while staging (fused LayerNorm).
// ---------------------------------------------------------------------------
template<bool ADD, bool LN>
__global__ __launch_bounds__(256) void gemm128(const float* __restrict__ A,
                                               const float* __restrict__ B,
                                               const float* __restrict__ Add,
                                               float* __restrict__ C,
                                               const float* __restrict__ stats,
                                               const float* __restrict__ lng,
                                               const float* __restrict__ lnb,
                                               int M, int N, int K) {
    __shared__ float As[16][132];
    __shared__ float Bs[16][132];
    __shared__ float muS[128], rsS[128];
    const int tid  = threadIdx.x;
    const int row0 = blockIdx.y * 128, col0 = blockIdx.x * 128;
    const int ty = tid >> 4, tx = tid & 15;

    if (LN) {
        if (tid < 128) {
            muS[tid] = stats[(size_t)(row0 + tid) * 2 + 0];
            rsS[tid] = stats[(size_t)(row0 + tid) * 2 + 1];
        }
        __syncthreads();
    }

    float acc[8][8];
    #pragma unroll
    for (int i = 0; i < 8; i++)
        #pragma unroll
        for (int j = 0; j < 8; j++) acc[i][j] = 0.f;

    const int ar0 = tid >> 2, akq = (tid & 3) * 4;    // A: row, k-quad
    const int bk0 = tid >> 5, bnq = (tid & 31) * 4;   // B: k, n-quad

    for (int k0 = 0; k0 < K; k0 += 16) {
        float4 gv, bv;
        if (LN) {
            gv = *(const float4*)(lng + k0 + akq);
            bv = *(const float4*)(lnb + k0 + akq);
        }
        #pragma unroll
        for (int i = 0; i < 2; i++) {
            const int r = ar0 + i * 64;
            float4 av = *(const float4*)(A + (size_t)(row0 + r) * K + k0 + akq);
            if (LN) {
                const float mu = muS[r], rs = rsS[r];
                av.x = (av.x - mu) * rs * gv.x + bv.x;
                av.y = (av.y - mu) * rs * gv.y + bv.y;
                av.z = (av.z - mu) * rs * gv.z + bv.z;
                av.w = (av.w - mu) * rs * gv.w + bv.w;
            }
            As[akq + 0][r] = av.x; As[akq + 1][r] = av.y;
            As[akq + 2][r] = av.z; As[akq + 3][r] = av.w;
        }
        #pragma unroll
        for (int i = 0; i < 2; i++) {
            const int k = bk0 + i * 8;
            const float4 bvv = *(const float4*)(B + (size_t)(k0 + k) * N + col0 + bnq);
            *(float4*)&Bs[k][bnq] = bvv;
        }
        __syncthreads();
        #pragma unroll
        for (int k = 0; k < 16; k++) {
            float a[8], bb[8];
            *(float4*)&a[0]  = *(const float4*)&As[k][ty * 4];
            *(float4*)&a[4]  = *(const float4*)&As[k][64 + ty * 4];
            *(float4*)&bb[0] = *(const float4*)&Bs[k][tx * 4];
            *(float4*)&bb[4] = *(const float4*)&Bs[k][64 + tx * 4];
            #pragma unroll
            for (int i = 0; i < 8; i++)
                #pragma unroll
                for (int j = 0; j < 8; j++)
                    acc[i][j] = fmaf(a[i], bb[j], acc[i][j]);
        }
        __syncthreads();
    }
    #pragma unroll
    for (int i = 0; i < 8; i++) {
        const int row = row0 + (i >> 2) * 64 + ty * 4 + (i & 3);
        #pragma unroll
        for (int jg = 0; jg < 2; jg++) {
            const int col = col0 + jg * 64 + tx * 4;
            float4 v = {acc[i][jg * 4 + 0], acc[i][jg * 4 + 1],
                        acc[i][jg * 4 + 2], acc[i][jg * 4 + 3]};
            if (ADD) {
                const float4 xv = *(const float4*)(Add + (size_t)row * N + col);
                v.x += xv.x; v.y += xv.y; v.z += xv.z; v.w += xv.w;
            }
            *(float4*)(C + (size_t)row * N + col) = v;
        }
    }
}

// ---------------------------------------------------------------------------
// 3. depthwise causal conv(4) + bias + SiLU.  u = xz[:, :2048]
// ---------------------------------------------------------------------------
__global__ __launch_bounds__(256) void conv_silu_kernel(const float* __restrict__ xz,
                                                        const float* __restrict__ cw,
                                                        const float* __restrict__ cb,
                                                        float* __restrict__ uc) {
    const int d  = blockIdx.x * 256 + threadIdx.x;
    const int b  = blockIdx.z;
    const int l0 = blockIdx.y * 16;
    const float w0 = cw[d * 4 + 0], w1 = cw[d * 4 + 1];
    const float w2 = cw[d * 4 + 2], w3 = cw[d * 4 + 3];
    const float bias = cb[d];
    const float* up = xz + (size_t)(b * LL) * (2 * DI) + d;
    float x0 = (l0 - 3 >= 0) ? up[(size_t)(l0 - 3) * (2 * DI)] : 0.f;
    float x1 = (l0 - 2 >= 0) ? up[(size_t)(l0 - 2) * (2 * DI)] : 0.f;
    float x2 = (l0 - 1 >= 0) ? up[(size_t)(l0 - 1) * (2 * DI)] : 0.f;
    float* op = uc + (size_t)(b * LL + l0) * DI + d;
    #pragma unroll
    for (int i = 0; i < 16; i++) {
        const float x3 = up[(size_t)(l0 + i) * (2 * DI)];
        const float v  = bias + w0 * x0 + w1 * x1 + w2 * x2 + w3 * x3;
        op[(size_t)i * DI] = v / (1.f + expf(-v));
        x0 = x1; x1 = x2; x2 = x3;
    }
}

// ---------------------------------------------------------------------------
// 4. dbc[row, c] = sum_k uc[row,k] * W_x[k,c]    (N=96)
// ---------------------------------------------------------------------------
__global__ __launch_bounds__(128) void dbc_kernel(const float* __restrict__ uc,
                                                  const float* __restrict__ Wx,
                                                  float* __restrict__ dbc) {
    __shared__ float us[8][DI];
    const int r0  = blockIdx.x * 8;
    const int tid = threadIdx.x;
    const float4* src = (const float4*)(uc + (size_t)r0 * DI);
    float4* dst = (float4*)&us[0][0];
    for (int i = tid; i < 8 * DI / 4; i += 128) dst[i] = src[i];
    __syncthreads();
    const int c = tid;
    if (c < 96) {
        float acc[8] = {0, 0, 0, 0, 0, 0, 0, 0};
        #pragma unroll 4
        for (int k = 0; k < DI; k++) {
            const float wv = Wx[k * 96 + c];
            #pragma unroll
            for (int r = 0; r < 8; r++) acc[r] += us[r][k] * wv;
        }
        #pragma unroll
        for (int r = 0; r < 8; r++) dbc[(size_t)(r0 + r) * 96 + c] = acc[r];
    }
}

// ---------------------------------------------------------------------------
// 5. softplus(dbc[:, :64] @ W_dt + b_dt) written into xz[:, 0:2048]
//    (u columns of xz are dead after the conv; row stride is 4096)
// ---------------------------------------------------------------------------
__global__ __launch_bounds__(256) void dt_kernel(const float* __restrict__ dbc,
                                                 const float* __restrict__ Wdt,
                                                 const float* __restrict__ bdt,
                                                 float* __restrict__ dtx) {
    __shared__ float ds[16][64];
    const int r0  = blockIdx.y * 16;
    const int tid = threadIdx.x;
    const int c   = blockIdx.x * 256 + tid;
    {
        const int r = tid >> 4, k4 = (tid & 15) * 4;
        *(float4*)&ds[r][k4] = *(const float4*)(dbc + (size_t)(r0 + r) * 96 + k4);
    }
    __syncthreads();
    float acc[16];
    #pragma unroll
    for (int r = 0; r < 16; r++) acc[r] = 0.f;
    #pragma unroll 4
    for (int k = 0; k < 64; k++) {
        const float wv = Wdt[k * DI + c];
        #pragma unroll
        for (int r = 0; r < 16; r++) acc[r] += ds[r][k] * wv;
    }
    const float bb = bdt[c];
    #pragma unroll
    for (int r = 0; r < 16; r++) {
        const float v = acc[r] + bb;
        dtx[(size_t)(r0 + r) * (2 * DI) + c] = (v > 20.f) ? v : log1pf(expf(v));
    }
}

// ---------------------------------------------------------------------------
// 6. selective scan, fused with D-skip and SiLU(z) gating.
//    dt lives in xz[:, 0:2048] (stride 4096); z in xz[:, 2048:4096].
//    thread = (b, d, s); 16 states reduced with shfl_xor; writes yg over uc.
// ---------------------------------------------------------------------------
__global__ __launch_bounds__(256) void scan_kernel(const float* __restrict__ xz,
                                                   const float* __restrict__ uc,
                                                   const float* __restrict__ dbc,
                                                   const float* __restrict__ A_log,
                                                   const float* __restrict__ Dskip,
                                                   float* __restrict__ yg) {
    const int tid = threadIdx.x;
    const int s   = tid & 15;
    const int dl  = tid >> 4;                  // 0..15
    const int b   = blockIdx.x >> 7;           // 128 blocks per batch
    const int d   = (blockIdx.x & 127) * 16 + dl;
    const float a   = -expf(A_log[d * DST + s]);
    const float dsk = Dskip[d];
    float h = 0.f;
    const size_t row0 = (size_t)b * LL;
    const float* dtp = xz  + row0 * (2 * DI) + d;            // dt in u-columns
    const float* zp  = xz  + row0 * (2 * DI) + DI + d;       // z columns
    const float* ucp = uc  + row0 * DI + d;
    const float* bp  = dbc + row0 * 96 + DTR + s;
    const float* cp  = dbc + row0 * 96 + DTR + DST + s;
    float*       yp  = yg  + row0 * DI + d;

    float dtv = dtp[0], ucv = ucp[0], Bv = bp[0], Cv = cp[0];
    for (int l = 0; l < LL; l++) {
        const int ln = (l + 1 < LL) ? (l + 1) : l;   // clamped prefetch
        const float dtn = dtp[(size_t)ln * (2 * DI)];
        const float ucn = ucp[(size_t)ln * DI];
        const float Bn  = bp[(size_t)ln * 96];
        const float Cn  = cp[(size_t)ln * 96];

        const float dA = expf(dtv * a);
        h = h * dA + (dtv * ucv) * Bv;
        float y = h * Cv;
        y += __shfl_xor(y, 1);
        y += __shfl_xor(y, 2);
        y += __shfl_xor(y, 4);
        y += __shfl_xor(y, 8);
        if (s == 0) {
            const float zv = zp[(size_t)l * (2 * DI)];
            const float yt = y + ucv * dsk;
            yp[(size_t)l * DI] = yt * (zv / (1.f + expf(-zv)));
        }
        dtv = dtn; ucv = ucn; Bv = Bn; Cv = Cn;
    }
}

// ---------------------------------------------------------------------------
extern "C" void kernel_launch(void* const* d_in, const int* in_sizes, int n_in,
                              void* d_out, int out_size, void* d_ws, size_t ws_size,
                              hipStream_t stream) {
    const float* x      = (const float*)d_in[0];
    const float* ln_g   = (const float*)d_in[1];
    const float* ln_b   = (const float*)d_in[2];
    const float* W_in   = (const float*)d_in[3];
    const float* conv_w = (const float*)d_in[4];
    const float* conv_b = (const float*)d_in[5];
    const float* W_x    = (const float*)d_in[6];
    const float* W_dt   = (const float*)d_in[7];
    const float* b_dt   = (const float*)d_in[8];
    const float* A_log  = (const float*)d_in[9];
    const float* Dskip  = (const float*)d_in[10];
    const float* W_out  = (const float*)d_in[11];
    float* out = (float*)d_out;

    // workspace layout (floats): 195.1 MB total
    float* ws    = (float*)d_ws;
    float* xz    = ws;                                 // 8192*4096  (u->dt | z)
    float* uc    = xz + (size_t)ROWS * 2 * DI;         // 8192*2048  (uc -> yg)
    float* dbc   = uc + (size_t)ROWS * DI;             // 8192*96
    float* stats = dbc + (size_t)ROWS * 96;            // 8192*2

    ln_stats_kernel<<<ROWS, 256, 0, stream>>>(x, stats);
    gemm128<false, true><<<dim3(2 * DI / 128, ROWS / 128), 256, 0, stream>>>(
        x, W_in, nullptr, xz, stats, ln_g, ln_b, ROWS, 2 * DI, DM);
    conv_silu_kernel<<<dim3(DI / 256, LL / 16, BB), 256, 0, stream>>>(
        xz, conv_w, conv_b, uc);
    dbc_kernel<<<ROWS / 8, 128, 0, stream>>>(uc, W_x, dbc);
    dt_kernel<<<dim3(DI / 256, ROWS / 16), 256, 0, stream>>>(dbc, W_dt, b_dt, xz);
    scan_kernel<<<BB * (DI / 16), 256, 0, stream>>>(
        xz, uc, dbc, A_log, Dskip, uc /* in-place gated y */);
    gemm128<true, false><<<dim3(DM / 128, ROWS / 128), 256, 0, stream>>>(
        uc, W_out, x, out, nullptr, nullptr, nullptr, ROWS, DM, DI);
}

// Round 3
// 2388.150 us; speedup vs baseline: 1.3920x; 1.3920x over previous
//
#include <hip/hip_runtime.h>
#include <hip/hip_bf16.h>

// Problem constants
#define BB 4
#define LL 2048
#define DM 1024
#define DI 2048          // D_INNER
#define DST 16           // D_STATE
#define DTR 64           // DT_RANK
#define ROWS (BB*LL)     // 8192
#define NC 16            // scan chunks
#define CHUNK (LL/NC)    // 128

// ---------------------------------------------------------------------------
// 1. LN stats: per-row mu and rsqrt(var+eps)  -> stats[row*2 + {0,1}]
// ---------------------------------------------------------------------------
__global__ __launch_bounds__(256) void ln_stats_kernel(const float* __restrict__ x,
                                                       float* __restrict__ stats) {
    const int row = blockIdx.x;
    const int tid = threadIdx.x;
    const float4 v = ((const float4*)(x + (size_t)row * DM))[tid];
    float s  = v.x + v.y + v.z + v.w;
    float sq = v.x*v.x + v.y*v.y + v.z*v.z + v.w*v.w;
    #pragma unroll
    for (int m = 1; m < 64; m <<= 1) {
        s  += __shfl_xor(s, m);
        sq += __shfl_xor(sq, m);
    }
    __shared__ float ss[4], ssq[4];
    const int w = tid >> 6;
    if ((tid & 63) == 0) { ss[w] = s; ssq[w] = sq; }
    __syncthreads();
    if (tid == 0) {
        s  = ss[0] + ss[1] + ss[2] + ss[3];
        sq = ssq[0] + ssq[1] + ssq[2] + ssq[3];
        const float mu  = s * (1.f / DM);
        const float var = sq * (1.f / DM) - mu * mu;
        stats[row * 2 + 0] = mu;
        stats[row * 2 + 1] = rsqrtf(var + 1e-5f);
    }
}

// ---------------------------------------------------------------------------
// 2. f32 tiled GEMM: C[M,N] = A[M,K] @ B[K,N] (+ Add).  128x128 tile, BK=16.
//    LN=true: A is raw x; apply (a-mu)*rs*g+b while staging (fused LayerNorm).
// ---------------------------------------------------------------------------
template<bool ADD, bool LN>
__global__ __launch_bounds__(256) void gemm128(const float* __restrict__ A,
                                               const float* __restrict__ B,
                                               const float* __restrict__ Add,
                                               float* __restrict__ C,
                                               const float* __restrict__ stats,
                                               const float* __restrict__ lng,
                                               const float* __restrict__ lnb,
                                               int M, int N, int K) {
    __shared__ float As[16][132];
    __shared__ float Bs[16][132];
    __shared__ float muS[128], rsS[128];
    const int tid  = threadIdx.x;
    const int row0 = blockIdx.y * 128, col0 = blockIdx.x * 128;
    const int ty = tid >> 4, tx = tid & 15;

    if (LN) {
        if (tid < 128) {
            muS[tid] = stats[(size_t)(row0 + tid) * 2 + 0];
            rsS[tid] = stats[(size_t)(row0 + tid) * 2 + 1];
        }
        __syncthreads();
    }

    float acc[8][8];
    #pragma unroll
    for (int i = 0; i < 8; i++)
        #pragma unroll
        for (int j = 0; j < 8; j++) acc[i][j] = 0.f;

    const int ar0 = tid >> 2, akq = (tid & 3) * 4;    // A: row, k-quad
    const int bk0 = tid >> 5, bnq = (tid & 31) * 4;   // B: k, n-quad

    for (int k0 = 0; k0 < K; k0 += 16) {
        float4 gv, bv;
        if (LN) {
            gv = *(const float4*)(lng + k0 + akq);
            bv = *(const float4*)(lnb + k0 + akq);
        }
        #pragma unroll
        for (int i = 0; i < 2; i++) {
            const int r = ar0 + i * 64;
            float4 av = *(const float4*)(A + (size_t)(row0 + r) * K + k0 + akq);
            if (LN) {
                const float mu = muS[r], rs = rsS[r];
                av.x = (av.x - mu) * rs * gv.x + bv.x;
                av.y = (av.y - mu) * rs * gv.y + bv.y;
                av.z = (av.z - mu) * rs * gv.z + bv.z;
                av.w = (av.w - mu) * rs * gv.w + bv.w;
            }
            As[akq + 0][r] = av.x; As[akq + 1][r] = av.y;
            As[akq + 2][r] = av.z; As[akq + 3][r] = av.w;
        }
        #pragma unroll
        for (int i = 0; i < 2; i++) {
            const int k = bk0 + i * 8;
            const float4 bvv = *(const float4*)(B + (size_t)(k0 + k) * N + col0 + bnq);
            *(float4*)&Bs[k][bnq] = bvv;
        }
        __syncthreads();
        #pragma unroll
        for (int k = 0; k < 16; k++) {
            float a[8], bb[8];
            *(float4*)&a[0]  = *(const float4*)&As[k][ty * 4];
            *(float4*)&a[4]  = *(const float4*)&As[k][64 + ty * 4];
            *(float4*)&bb[0] = *(const float4*)&Bs[k][tx * 4];
            *(float4*)&bb[4] = *(const float4*)&Bs[k][64 + tx * 4];
            #pragma unroll
            for (int i = 0; i < 8; i++)
                #pragma unroll
                for (int j = 0; j < 8; j++)
                    acc[i][j] = fmaf(a[i], bb[j], acc[i][j]);
        }
        __syncthreads();
    }
    #pragma unroll
    for (int i = 0; i < 8; i++) {
        const int row = row0 + (i >> 2) * 64 + ty * 4 + (i & 3);
        #pragma unroll
        for (int jg = 0; jg < 2; jg++) {
            const int col = col0 + jg * 64 + tx * 4;
            float4 v = {acc[i][jg * 4 + 0], acc[i][jg * 4 + 1],
                        acc[i][jg * 4 + 2], acc[i][jg * 4 + 3]};
            if (ADD) {
                const float4 xv = *(const float4*)(Add + (size_t)row * N + col);
                v.x += xv.x; v.y += xv.y; v.z += xv.z; v.w += xv.w;
            }
            *(float4*)(C + (size_t)row * N + col) = v;
        }
    }
}

// ---------------------------------------------------------------------------
// 3. depthwise causal conv(4) + bias + SiLU.  u = xz[:, :2048]
// ---------------------------------------------------------------------------
__global__ __launch_bounds__(256) void conv_silu_kernel(const float* __restrict__ xz,
                                                        const float* __restrict__ cw,
                                                        const float* __restrict__ cb,
                                                        float* __restrict__ uc) {
    const int d  = blockIdx.x * 256 + threadIdx.x;
    const int b  = blockIdx.z;
    const int l0 = blockIdx.y * 16;
    const float w0 = cw[d * 4 + 0], w1 = cw[d * 4 + 1];
    const float w2 = cw[d * 4 + 2], w3 = cw[d * 4 + 3];
    const float bias = cb[d];
    const float* up = xz + (size_t)(b * LL) * (2 * DI) + d;
    float x0 = (l0 - 3 >= 0) ? up[(size_t)(l0 - 3) * (2 * DI)] : 0.f;
    float x1 = (l0 - 2 >= 0) ? up[(size_t)(l0 - 2) * (2 * DI)] : 0.f;
    float x2 = (l0 - 1 >= 0) ? up[(size_t)(l0 - 1) * (2 * DI)] : 0.f;
    float* op = uc + (size_t)(b * LL + l0) * DI + d;
    #pragma unroll
    for (int i = 0; i < 16; i++) {
        const float x3 = up[(size_t)(l0 + i) * (2 * DI)];
        const float v  = bias + w0 * x0 + w1 * x1 + w2 * x2 + w3 * x3;
        op[(size_t)i * DI] = v / (1.f + expf(-v));
        x0 = x1; x1 = x2; x2 = x3;
    }
}

// ---------------------------------------------------------------------------
// 4. dbc[row, c] = sum_k uc[row,k] * W_x[k,c]    (N=96)
// ---------------------------------------------------------------------------
__global__ __launch_bounds__(128) void dbc_kernel(const float* __restrict__ uc,
                                                  const float* __restrict__ Wx,
                                                  float* __restrict__ dbc) {
    __shared__ float us[8][DI];
    const int r0  = blockIdx.x * 8;
    const int tid = threadIdx.x;
    const float4* src = (const float4*)(uc + (size_t)r0 * DI);
    float4* dst = (float4*)&us[0][0];
    for (int i = tid; i < 8 * DI / 4; i += 128) dst[i] = src[i];
    __syncthreads();
    const int c = tid;
    if (c < 96) {
        float acc[8] = {0, 0, 0, 0, 0, 0, 0, 0};
        #pragma unroll 4
        for (int k = 0; k < DI; k++) {
            const float wv = Wx[k * 96 + c];
            #pragma unroll
            for (int r = 0; r < 8; r++) acc[r] += us[r][k] * wv;
        }
        #pragma unroll
        for (int r = 0; r < 8; r++) dbc[(size_t)(r0 + r) * 96 + c] = acc[r];
    }
}

// ---------------------------------------------------------------------------
// 5. softplus(dbc[:, :64] @ W_dt + b_dt) written into xz[:, 0:2048]
// ---------------------------------------------------------------------------
__global__ __launch_bounds__(256) void dt_kernel(const float* __restrict__ dbc,
                                                 const float* __restrict__ Wdt,
                                                 const float* __restrict__ bdt,
                                                 float* __restrict__ dtx) {
    __shared__ float ds[16][64];
    const int r0  = blockIdx.y * 16;
    const int tid = threadIdx.x;
    const int c   = blockIdx.x * 256 + tid;
    {
        const int r = tid >> 4, k4 = (tid & 15) * 4;
        *(float4*)&ds[r][k4] = *(const float4*)(dbc + (size_t)(r0 + r) * 96 + k4);
    }
    __syncthreads();
    float acc[16];
    #pragma unroll
    for (int r = 0; r < 16; r++) acc[r] = 0.f;
    #pragma unroll 4
    for (int k = 0; k < 64; k++) {
        const float wv = Wdt[k * DI + c];
        #pragma unroll
        for (int r = 0; r < 16; r++) acc[r] += ds[r][k] * wv;
    }
    const float bb = bdt[c];
    #pragma unroll
    for (int r = 0; r < 16; r++) {
        const float v = acc[r] + bb;
        dtx[(size_t)(r0 + r) * (2 * DI) + c] = (v > 20.f) ? v : log1pf(expf(v));
    }
}

// ---------------------------------------------------------------------------
// 6a. scan pass 1: per-chunk local scan from h=0; store (h_partial, P=prod dA).
//     thread=(dl,s); block=(dgroup, chunk, b).  dt lives in xz[:, :2048].
// ---------------------------------------------------------------------------
__global__ __launch_bounds__(256) void scan_pass1_kernel(const float* __restrict__ xz,
                                                         const float* __restrict__ uc,
                                                         const float* __restrict__ dbc,
                                                         const float* __restrict__ A_log,
                                                         float* __restrict__ hbuf,
                                                         float* __restrict__ Pbuf) {
    const int tid = threadIdx.x;
    const int s   = tid & 15;
    const int dl  = tid >> 4;
    const int d   = blockIdx.x * 16 + dl;
    const int c   = blockIdx.y;
    const int b   = blockIdx.z;
    const float a = -expf(A_log[d * DST + s]);
    const size_t row0 = (size_t)b * LL + (size_t)c * CHUNK;
    const float* dtp = xz  + row0 * (2 * DI) + d;
    const float* ucp = uc  + row0 * DI + d;
    const float* bp  = dbc + row0 * 96 + DTR + s;

    float h = 0.f, P = 1.f;
    float dtv = dtp[0], ucv = ucp[0], Bv = bp[0];
    for (int l = 0; l < CHUNK; l++) {
        const int ln = (l + 1 < CHUNK) ? (l + 1) : l;
        const float dtn = dtp[(size_t)ln * (2 * DI)];
        const float ucn = ucp[(size_t)ln * DI];
        const float Bn  = bp[(size_t)ln * 96];
        const float dA = expf(dtv * a);
        h = h * dA + (dtv * ucv) * Bv;
        P *= dA;
        dtv = dtn; ucv = ucn; Bv = Bn;
    }
    const size_t idx = (((size_t)b * NC + c) * DI + d) * DST + s;
    hbuf[idx] = h;
    Pbuf[idx] = P;
}

// ---------------------------------------------------------------------------
// 6b. scan combine: sequential over chunks, rewrite hbuf[c] := h_in for chunk c.
//     H_{-1}=0;  h_in_c = H_{c-1};  H_c = h_partial_c + P_c * H_{c-1}.
// ---------------------------------------------------------------------------
__global__ __launch_bounds__(256) void scan_combine_kernel(float* __restrict__ hbuf,
                                                           const float* __restrict__ Pbuf) {
    const size_t gid = (size_t)blockIdx.x * 256 + threadIdx.x;   // over B*DI*DST
    const size_t b   = gid >> 15;              // DI*DST = 32768
    const size_t d16s = gid & 32767;
    float H = 0.f;
    #pragma unroll
    for (int c = 0; c < NC; c++) {
        const size_t idx = (b * NC + c) * (DI * DST) + d16s;
        const float hc = hbuf[idx];
        const float Pc = Pbuf[idx];
        hbuf[idx] = H;
        H = hc + Pc * H;
    }
}

// ---------------------------------------------------------------------------
// 6c. scan pass 3: re-scan chunk from true h_in; y, D-skip, SiLU(z) gate.
//     Writes yg over uc in place.
// ---------------------------------------------------------------------------
__global__ __launch_bounds__(256) void scan_pass3_kernel(const float* __restrict__ xz,
                                                         const float* __restrict__ uc,
                                                         const float* __restrict__ dbc,
                                                         const float* __restrict__ A_log,
                                                         const float* __restrict__ Dskip,
                                                         const float* __restrict__ hbuf,
                                                         float* __restrict__ yg) {
    const int tid = threadIdx.x;
    const int s   = tid & 15;
    const int dl  = tid >> 4;
    const int d   = blockIdx.x * 16 + dl;
    const int c   = blockIdx.y;
    const int b   = blockIdx.z;
    const float a   = -expf(A_log[d * DST + s]);
    const float dsk = Dskip[d];
    const size_t row0 = (size_t)b * LL + (size_t)c * CHUNK;
    const float* dtp = xz  + row0 * (2 * DI) + d;
    const float* zp  = xz  + row0 * (2 * DI) + DI + d;
    const float* ucp = uc  + row0 * DI + d;
    const float* bp  = dbc + row0 * 96 + DTR + s;
    const float* cp  = dbc + row0 * 96 + DTR + DST + s;
    float*       yp  = yg  + row0 * DI + d;

    float h = hbuf[(((size_t)b * NC + c) * DI + d) * DST + s];
    float dtv = dtp[0], ucv = ucp[0], Bv = bp[0], Cv = cp[0];
    for (int l = 0; l < CHUNK; l++) {
        const int ln = (l + 1 < CHUNK) ? (l + 1) : l;
        const float dtn = dtp[(size_t)ln * (2 * DI)];
        const float ucn = ucp[(size_t)ln * DI];
        const float Bn  = bp[(size_t)ln * 96];
        const float Cn  = cp[(size_t)ln * 96];

        const float dA = expf(dtv * a);
        h = h * dA + (dtv * ucv) * Bv;
        float y = h * Cv;
        y += __shfl_xor(y, 1);
        y += __shfl_xor(y, 2);
        y += __shfl_xor(y, 4);
        y += __shfl_xor(y, 8);
        if (s == 0) {
            const float zv = zp[(size_t)l * (2 * DI)];
            const float yt = y + ucv * dsk;
            yp[(size_t)l * DI] = yt * (zv / (1.f + expf(-zv)));
        }
        dtv = dtn; ucv = ucn; Bv = Bn; Cv = Cn;
    }
}

// ---------------------------------------------------------------------------
extern "C" void kernel_launch(void* const* d_in, const int* in_sizes, int n_in,
                              void* d_out, int out_size, void* d_ws, size_t ws_size,
                              hipStream_t stream) {
    const float* x      = (const float*)d_in[0];
    const float* ln_g   = (const float*)d_in[1];
    const float* ln_b   = (const float*)d_in[2];
    const float* W_in   = (const float*)d_in[3];
    const float* conv_w = (const float*)d_in[4];
    const float* conv_b = (const float*)d_in[5];
    const float* W_x    = (const float*)d_in[6];
    const float* W_dt   = (const float*)d_in[7];
    const float* b_dt   = (const float*)d_in[8];
    const float* A_log  = (const float*)d_in[9];
    const float* Dskip  = (const float*)d_in[10];
    const float* W_out  = (const float*)d_in[11];
    float* out = (float*)d_out;

    // workspace layout (floats): ~195 MB total
    float* ws    = (float*)d_ws;
    float* xz    = ws;                                 // 8192*4096  (u->dt | z)
    float* uc    = xz + (size_t)ROWS * 2 * DI;         // 8192*2048  (uc -> yg)
    float* dbc   = uc + (size_t)ROWS * DI;             // 8192*96
    float* stats = dbc + (size_t)ROWS * 96;            // 8192*2
    // scan chunk scratch lives in d_out (32 MB, dead until final GEMM):
    float* hbuf  = out;                                // BB*NC*DI*DST = 2M floats
    float* Pbuf  = out + (size_t)BB * NC * DI * DST;   // 2M floats (16 MB total)

    ln_stats_kernel<<<ROWS, 256, 0, stream>>>(x, stats);
    gemm128<false, true><<<dim3(2 * DI / 128, ROWS / 128), 256, 0, stream>>>(
        x, W_in, nullptr, xz, stats, ln_g, ln_b, ROWS, 2 * DI, DM);
    conv_silu_kernel<<<dim3(DI / 256, LL / 16, BB), 256, 0, stream>>>(
        xz, conv_w, conv_b, uc);
    dbc_kernel<<<ROWS / 8, 128, 0, stream>>>(uc, W_x, dbc);
    dt_kernel<<<dim3(DI / 256, ROWS / 16), 256, 0, stream>>>(dbc, W_dt, b_dt, xz);
    scan_pass1_kernel<<<dim3(DI / 16, NC, BB), 256, 0, stream>>>(
        xz, uc, dbc, A_log, hbuf, Pbuf);
    scan_combine_kernel<<<(BB * DI * DST) / 256, 256, 0, stream>>>(hbuf, Pbuf);
    scan_pass3_kernel<<<dim3(DI / 16, NC, BB), 256, 0, stream>>>(
        xz, uc, dbc, A_log, Dskip, hbuf, uc /* in-place gated y */);
    gemm128<true, false><<<dim3(DM / 128, ROWS / 128), 256, 0, stream>>>(
        uc, W_out, x, out, nullptr, nullptr, nullptr, ROWS, DM, DI);
}

// Round 4
// 1057.932 us; speedup vs baseline: 3.1422x; 2.2574x over previous
//
#include <hip/hip_runtime.h>
#include <hip/hip_bf16.h>

// Problem constants
#define BB 4
#define LL 2048
#define DM 1024
#define DI 2048          // D_INNER
#define DST 16           // D_STATE
#define DTR 64           // DT_RANK
#define ROWS (BB*LL)     // 8192
#define NC 16            // scan chunks
#define CHUNK (LL/NC)    // 128

using bf16x8 = __attribute__((ext_vector_type(8))) __bf16;
using f32x4  = __attribute__((ext_vector_type(4))) float;

#define AS1 __attribute__((address_space(1)))
#define AS3 __attribute__((address_space(3)))

// ---------------------------------------------------------------------------
// 0. transpose + f32->bf16: dst[c][r] = src[r][c], zero-pad c in [C, Cpad)
// ---------------------------------------------------------------------------
__global__ __launch_bounds__(256) void transpose_bf16_kernel(const float* __restrict__ src,
                                                             __hip_bfloat16* __restrict__ dst,
                                                             int R, int C, int Cpad) {
    __shared__ float t[32][33];
    const int c0 = blockIdx.x * 32, r0 = blockIdx.y * 32;
    const int tx = threadIdx.x & 31, ty = threadIdx.x >> 5;   // 32 x 8
    #pragma unroll
    for (int k = 0; k < 4; k++) {
        const int r = r0 + ty + 8 * k, c = c0 + tx;
        t[ty + 8 * k][tx] = (r < R && c < C) ? src[(size_t)r * C + c] : 0.f;
    }
    __syncthreads();
    #pragma unroll
    for (int k = 0; k < 4; k++) {
        const int c = c0 + ty + 8 * k, r = r0 + tx;
        if (c < Cpad && r < R) dst[(size_t)c * R + r] = __float2bfloat16(t[tx][ty + 8 * k]);
    }
}

// ---------------------------------------------------------------------------
// 1. fused LayerNorm -> bf16:  xn[row,:] = bf16((x-mu)*rsqrt(var+eps)*g + b)
// ---------------------------------------------------------------------------
__global__ __launch_bounds__(256) void ln_bf16_kernel(const float* __restrict__ x,
                                                      const float* __restrict__ g,
                                                      const float* __restrict__ bta,
                                                      __hip_bfloat16* __restrict__ xn) {
    const int row = blockIdx.x;
    const int tid = threadIdx.x;
    const float4 v = ((const float4*)(x + (size_t)row * DM))[tid];
    float s  = v.x + v.y + v.z + v.w;
    float sq = v.x*v.x + v.y*v.y + v.z*v.z + v.w*v.w;
    #pragma unroll
    for (int m = 1; m < 64; m <<= 1) {
        s  += __shfl_xor(s, m);
        sq += __shfl_xor(sq, m);
    }
    __shared__ float ss[4], ssq[4];
    const int w = tid >> 6;
    if ((tid & 63) == 0) { ss[w] = s; ssq[w] = sq; }
    __syncthreads();
    s  = ss[0] + ss[1] + ss[2] + ss[3];
    sq = ssq[0] + ssq[1] + ssq[2] + ssq[3];
    const float mu  = s * (1.f / DM);
    const float var = sq * (1.f / DM) - mu * mu;
    const float rs  = rsqrtf(var + 1e-5f);
    const float4 gv = ((const float4*)g)[tid];
    const float4 bv = ((const float4*)bta)[tid];
    __hip_bfloat16* op = xn + (size_t)row * DM + tid * 4;
    op[0] = __float2bfloat16((v.x - mu) * rs * gv.x + bv.x);
    op[1] = __float2bfloat16((v.y - mu) * rs * gv.y + bv.y);
    op[2] = __float2bfloat16((v.z - mu) * rs * gv.z + bv.z);
    op[3] = __float2bfloat16((v.w - mu) * rs * gv.w + bv.w);
}

// ---------------------------------------------------------------------------
// 2. bf16 MFMA GEMM (m97 structure): C[M,128-col-tile] = A[M,K] @ Bt[N,K]^T
//    128x128 tile, BK=32, 256 thr = 4 waves, each wave 4x4 MFMA 16x16x32.
//    MODE 0: split epilogue -> O f32 (cols<DI), Oz bf16 (cols>=DI), stride DI
//    MODE 1: O f32, stride 128 (dbc)
//    MODE 2: O f32 = acc + Add, stride DM (final GEMM + residual)
// ---------------------------------------------------------------------------
template<int MODE>
__global__ __launch_bounds__(256) void mfma_gemm(const __hip_bfloat16* __restrict__ A,
                                                 const __hip_bfloat16* __restrict__ Bt,
                                                 float* __restrict__ O,
                                                 __hip_bfloat16* __restrict__ Oz,
                                                 const float* __restrict__ Add,
                                                 int K) {
    __shared__ __hip_bfloat16 As[128 * 32];
    __shared__ __hip_bfloat16 Bs[128 * 32];
    const int tid  = threadIdx.x;
    const int lane = tid & 63;
    const int w    = tid >> 6;
    const int row0 = blockIdx.y * 128, col0 = blockIdx.x * 128;
    const int wr0 = (w >> 1) * 64, wc0 = (w & 1) * 64;

    f32x4 acc[4][4];
    #pragma unroll
    for (int i = 0; i < 4; i++)
        #pragma unroll
        for (int j = 0; j < 4; j++) acc[i][j] = f32x4{0.f, 0.f, 0.f, 0.f};

    // staging: thread covers 16B = 8 bf16; row = tid/4, kq = (tid&3)*8
    const int sm = tid >> 2;
    const int sk = (tid & 3) * 8;
    const __hip_bfloat16* gA = A  + (size_t)(row0 + sm) * K + sk;
    const __hip_bfloat16* gB = Bt + (size_t)(col0 + sm) * K + sk;
    __hip_bfloat16* lA = &As[tid * 8];
    __hip_bfloat16* lB = &Bs[tid * 8];
    const size_t g64 = (size_t)64 * K;

    const int fm = lane & 15;             // fragment row/col within 16
    const int fq = (lane >> 4) * 8;       // fragment k-offset

    for (int k0 = 0; k0 < K; k0 += 32) {
        __builtin_amdgcn_global_load_lds((const AS1 unsigned int*)(gA + k0),
                                         (AS3 unsigned int*)lA, 16, 0, 0);
        __builtin_amdgcn_global_load_lds((const AS1 unsigned int*)(gA + g64 + k0),
                                         (AS3 unsigned int*)(lA + 64 * 32), 16, 0, 0);
        __builtin_amdgcn_global_load_lds((const AS1 unsigned int*)(gB + k0),
                                         (AS3 unsigned int*)lB, 16, 0, 0);
        __builtin_amdgcn_global_load_lds((const AS1 unsigned int*)(gB + g64 + k0),
                                         (AS3 unsigned int*)(lB + 64 * 32), 16, 0, 0);
        __syncthreads();
        bf16x8 af[4], bfr[4];
        #pragma unroll
        for (int i = 0; i < 4; i++)
            af[i] = *(const bf16x8*)&As[(wr0 + i * 16 + fm) * 32 + fq];
        #pragma unroll
        for (int j = 0; j < 4; j++)
            bfr[j] = *(const bf16x8*)&Bs[(wc0 + j * 16 + fm) * 32 + fq];
        #pragma unroll
        for (int i = 0; i < 4; i++)
            #pragma unroll
            for (int j = 0; j < 4; j++)
                acc[i][j] = __builtin_amdgcn_mfma_f32_16x16x32_bf16(af[i], bfr[j], acc[i][j], 0, 0, 0);
        __syncthreads();
    }

    // epilogue: C/D layout col=lane&15, row=(lane>>4)*4+reg  [m89/m91 verified]
    #pragma unroll
    for (int i = 0; i < 4; i++) {
        #pragma unroll
        for (int j = 0; j < 4; j++) {
            #pragma unroll
            for (int r = 0; r < 4; r++) {
                const int row = row0 + wr0 + i * 16 + (lane >> 4) * 4 + r;
                const int col = col0 + wc0 + j * 16 + fm;
                const float v = acc[i][j][r];
                if (MODE == 0) {
                    if (col0 < DI) O[(size_t)row * DI + col] = v;
                    else           Oz[(size_t)row * DI + (col - DI)] = __float2bfloat16(v);
                } else if (MODE == 1) {
                    O[(size_t)row * 128 + col] = v;
                } else {
                    O[(size_t)row * DM + col] = v + Add[(size_t)row * DM + col];
                }
            }
        }
    }
}

// ---------------------------------------------------------------------------
// 3. depthwise causal conv(4) + bias + SiLU.  u f32 [rows][DI] -> uc bf16
// ---------------------------------------------------------------------------
__global__ __launch_bounds__(256) void conv_silu_kernel(const float* __restrict__ u,
                                                        const float* __restrict__ cw,
                                                        const float* __restrict__ cb,
                                                        __hip_bfloat16* __restrict__ uc) {
    const int d  = blockIdx.x * 256 + threadIdx.x;
    const int b  = blockIdx.z;
    const int l0 = blockIdx.y * 16;
    const float w0 = cw[d * 4 + 0], w1 = cw[d * 4 + 1];
    const float w2 = cw[d * 4 + 2], w3 = cw[d * 4 + 3];
    const float bias = cb[d];
    const float* up = u + (size_t)(b * LL) * DI + d;
    float x0 = (l0 - 3 >= 0) ? up[(size_t)(l0 - 3) * DI] : 0.f;
    float x1 = (l0 - 2 >= 0) ? up[(size_t)(l0 - 2) * DI] : 0.f;
    float x2 = (l0 - 1 >= 0) ? up[(size_t)(l0 - 1) * DI] : 0.f;
    __hip_bfloat16* op = uc + (size_t)(b * LL + l0) * DI + d;
    #pragma unroll
    for (int i = 0; i < 16; i++) {
        const float x3 = up[(size_t)(l0 + i) * DI];
        const float v  = bias + w0 * x0 + w1 * x1 + w2 * x2 + w3 * x3;
        op[(size_t)i * DI] = __float2bfloat16(v / (1.f + expf(-v)));
        x0 = x1; x1 = x2; x2 = x3;
    }
}

// ---------------------------------------------------------------------------
// 5. softplus(dbc[:, :64] @ W_dt + b_dt) written into u buffer (dt storage)
//    dbc stride 128 now.
// ---------------------------------------------------------------------------
__global__ __launch_bounds__(256) void dt_kernel(const float* __restrict__ dbc,
                                                 const float* __restrict__ Wdt,
                                                 const float* __restrict__ bdt,
                                                 float* __restrict__ dtx) {
    __shared__ float ds[16][64];
    const int r0  = blockIdx.y * 16;
    const int tid = threadIdx.x;
    const int c   = blockIdx.x * 256 + tid;
    {
        const int r = tid >> 4, k4 = (tid & 15) * 4;
        *(float4*)&ds[r][k4] = *(const float4*)(dbc + (size_t)(r0 + r) * 128 + k4);
    }
    __syncthreads();
    float acc[16];
    #pragma unroll
    for (int r = 0; r < 16; r++) acc[r] = 0.f;
    #pragma unroll 4
    for (int k = 0; k < 64; k++) {
        const float wv = Wdt[k * DI + c];
        #pragma unroll
        for (int r = 0; r < 16; r++) acc[r] += ds[r][k] * wv;
    }
    const float bb = bdt[c];
    #pragma unroll
    for (int r = 0; r < 16; r++) {
        const float v = acc[r] + bb;
        dtx[(size_t)(r0 + r) * DI + c] = (v > 20.f) ? v : log1pf(expf(v));
    }
}

// ---------------------------------------------------------------------------
// 6a. scan pass 1: per-chunk local scan from h=0; store (h_partial, P=prod dA)
// ---------------------------------------------------------------------------
__global__ __launch_bounds__(256) void scan_pass1_kernel(const float* __restrict__ dtb,
                                                         const __hip_bfloat16* __restrict__ uc,
                                                         const float* __restrict__ dbc,
                                                         const float* __restrict__ A_log,
                                                         float* __restrict__ hbuf,
                                                         float* __restrict__ Pbuf) {
    const int tid = threadIdx.x;
    const int s   = tid & 15;
    const int dl  = tid >> 4;
    const int d   = blockIdx.x * 16 + dl;
    const int c   = blockIdx.y;
    const int b   = blockIdx.z;
    const float a = -expf(A_log[d * DST + s]);
    const size_t row0 = (size_t)b * LL + (size_t)c * CHUNK;
    const float* dtp = dtb + row0 * DI + d;
    const __hip_bfloat16* ucp = uc + row0 * DI + d;
    const float* bp  = dbc + row0 * 128 + DTR + s;

    float h = 0.f, P = 1.f;
    float dtv = dtp[0], ucv = __bfloat162float(ucp[0]), Bv = bp[0];
    for (int l = 0; l < CHUNK; l++) {
        const int ln = (l + 1 < CHUNK) ? (l + 1) : l;
        const float dtn = dtp[(size_t)ln * DI];
        const float ucn = __bfloat162float(ucp[(size_t)ln * DI]);
        const float Bn  = bp[(size_t)ln * 128];
        const float dA = expf(dtv * a);
        h = h * dA + (dtv * ucv) * Bv;
        P *= dA;
        dtv = dtn; ucv = ucn; Bv = Bn;
    }
    const size_t idx = (((size_t)b * NC + c) * DI + d) * DST + s;
    hbuf[idx] = h;
    Pbuf[idx] = P;
}

// ---------------------------------------------------------------------------
// 6b. scan combine: rewrite hbuf[c] := h_in for chunk c
// ---------------------------------------------------------------------------
__global__ __launch_bounds__(256) void scan_combine_kernel(float* __restrict__ hbuf,
                                                           const float* __restrict__ Pbuf) {
    const size_t gid  = (size_t)blockIdx.x * 256 + threadIdx.x;
    const size_t b    = gid >> 15;             // DI*DST = 32768
    const size_t d16s = gid & 32767;
    float H = 0.f;
    #pragma unroll
    for (int c = 0; c < NC; c++) {
        const size_t idx = (b * NC + c) * (DI * DST) + d16s;
        const float hc = hbuf[idx];
        const float Pc = Pbuf[idx];
        hbuf[idx] = H;
        H = hc + Pc * H;
    }
}

// ---------------------------------------------------------------------------
// 6c. scan pass 3: re-scan from true h_in; y + D-skip + SiLU(z) gate.
//     Writes gated y as bf16 IN PLACE over uc (per-thread same addresses).
// ---------------------------------------------------------------------------
__global__ __launch_bounds__(256) void scan_pass3_kernel(const float* __restrict__ dtb,
                                                         __hip_bfloat16* uc,
                                                         const __hip_bfloat16* __restrict__ z,
                                                         const float* __restrict__ dbc,
                                                         const float* __restrict__ A_log,
                                                         const float* __restrict__ Dskip,
                                                         const float* __restrict__ hbuf) {
    const int tid = threadIdx.x;
    const int s   = tid & 15;
    const int dl  = tid >> 4;
    const int d   = blockIdx.x * 16 + dl;
    const int c   = blockIdx.y;
    const int b   = blockIdx.z;
    const float a   = -expf(A_log[d * DST + s]);
    const float dsk = Dskip[d];
    const size_t row0 = (size_t)b * LL + (size_t)c * CHUNK;
    const float* dtp = dtb + row0 * DI + d;
    const __hip_bfloat16* zp = z + row0 * DI + d;
    __hip_bfloat16* ucp = uc + row0 * DI + d;
    const float* bp  = dbc + row0 * 128 + DTR + s;
    const float* cp  = dbc + row0 * 128 + DTR + DST + s;

    float h = hbuf[(((size_t)b * NC + c) * DI + d) * DST + s];
    float dtv = dtp[0], ucv = __bfloat162float(ucp[0]), Bv = bp[0], Cv = cp[0];
    for (int l = 0; l < CHUNK; l++) {
        const int ln = (l + 1 < CHUNK) ? (l + 1) : l;
        const float dtn = dtp[(size_t)ln * DI];
        const float ucn = __bfloat162float(ucp[(size_t)ln * DI]);
        const float Bn  = bp[(size_t)ln * 128];
        const float Cn  = cp[(size_t)ln * 128];

        const float dA = expf(dtv * a);
        h = h * dA + (dtv * ucv) * Bv;
        float y = h * Cv;
        y += __shfl_xor(y, 1);
        y += __shfl_xor(y, 2);
        y += __shfl_xor(y, 4);
        y += __shfl_xor(y, 8);
        if (s == 0) {
            const float zv = __bfloat162float(zp[(size_t)l * DI]);
            const float yt = y + ucv * dsk;
            ucp[(size_t)l * DI] = __float2bfloat16(yt * (zv / (1.f + expf(-zv))));
        }
        dtv = dtn; ucv = ucn; Bv = Bn; Cv = Cn;
    }
}

// ---------------------------------------------------------------------------
extern "C" void kernel_launch(void* const* d_in, const int* in_sizes, int n_in,
                              void* d_out, int out_size, void* d_ws, size_t ws_size,
                              hipStream_t stream) {
    const float* x      = (const float*)d_in[0];
    const float* ln_g   = (const float*)d_in[1];
    const float* ln_b   = (const float*)d_in[2];
    const float* W_in   = (const float*)d_in[3];
    const float* conv_w = (const float*)d_in[4];
    const float* conv_b = (const float*)d_in[5];
    const float* W_x    = (const float*)d_in[6];
    const float* W_dt   = (const float*)d_in[7];
    const float* b_dt   = (const float*)d_in[8];
    const float* A_log  = (const float*)d_in[9];
    const float* Dskip  = (const float*)d_in[10];
    const float* W_out  = (const float*)d_in[11];
    float* out = (float*)d_out;

    // workspace layout (bytes), total 161 MB  (proven budget: 195 MB)
    const size_t MB = 1024ull * 1024ull;
    char* wsb = (char*)d_ws;
    float*          u     = (float*)(wsb);                     // 64 MB: u -> dt
    __hip_bfloat16* z     = (__hip_bfloat16*)(wsb + 64 * MB);  // 32 MB
    __hip_bfloat16* uc    = (__hip_bfloat16*)(wsb + 96 * MB);  // 32 MB: uc -> yg
    __hip_bfloat16* xn    = (__hip_bfloat16*)(wsb + 128 * MB); // 16 MB (-> hbuf/Pbuf)
    __hip_bfloat16* WinT  = (__hip_bfloat16*)(wsb + 144 * MB); // 8 MB  [4096][1024]
    __hip_bfloat16* WoutT = (__hip_bfloat16*)(wsb + 152 * MB); // 4 MB  [1024][2048]
    __hip_bfloat16* WxT   = (__hip_bfloat16*)(wsb + 156 * MB); // 0.5MB [128][2048]
    float*          dbc   = (float*)(wsb + 157 * MB);          // 4 MB  [8192][128]
    float* hbuf = (float*)xn;                                  // 8 MB (xn dead after GEMM1)
    float* Pbuf = hbuf + (size_t)BB * NC * DI * DST;           // 8 MB

    transpose_bf16_kernel<<<dim3(128, 32), 256, 0, stream>>>(W_in, WinT, DM, 2 * DI, 2 * DI);
    transpose_bf16_kernel<<<dim3(32, 64), 256, 0, stream>>>(W_out, WoutT, DI, DM, DM);
    transpose_bf16_kernel<<<dim3(4, 64), 256, 0, stream>>>(W_x, WxT, DI, 96, 128);
    ln_bf16_kernel<<<ROWS, 256, 0, stream>>>(x, ln_g, ln_b, xn);
    mfma_gemm<0><<<dim3(32, 64), 256, 0, stream>>>(xn, WinT, u, z, nullptr, DM);
    conv_silu_kernel<<<dim3(DI / 256, LL / 16, BB), 256, 0, stream>>>(u, conv_w, conv_b, uc);
    mfma_gemm<1><<<dim3(1, 64), 256, 0, stream>>>(uc, WxT, dbc, nullptr, nullptr, DI);
    dt_kernel<<<dim3(DI / 256, ROWS / 16), 256, 0, stream>>>(dbc, W_dt, b_dt, u);
    scan_pass1_kernel<<<dim3(DI / 16, NC, BB), 256, 0, stream>>>(u, uc, dbc, A_log, hbuf, Pbuf);
    scan_combine_kernel<<<(BB * DI * DST) / 256, 256, 0, stream>>>(hbuf, Pbuf);
    scan_pass3_kernel<<<dim3(DI / 16, NC, BB), 256, 0, stream>>>(u, uc, z, dbc, A_log, Dskip, hbuf);
    mfma_gemm<2><<<dim3(DM / 128, ROWS / 128), 256, 0, stream>>>(uc, WoutT, out, nullptr, x, DI);
}

// Round 5
// 588.054 us; speedup vs baseline: 5.6530x; 1.7990x over previous
//
#include <hip/hip_runtime.h>
#include <hip/hip_bf16.h>

// Problem constants
#define BB 4
#define LL 2048
#define DM 1024
#define DI 2048          // D_INNER
#define DST 16           // D_STATE
#define DTR 64           // DT_RANK
#define ROWS (BB*LL)     // 8192
#define NC 32            // scan chunks
#define CHUNK (LL/NC)    // 64

using bf16x8 = __attribute__((ext_vector_type(8))) __bf16;
using f32x4  = __attribute__((ext_vector_type(4))) float;

#define AS1 __attribute__((address_space(1)))
#define AS3 __attribute__((address_space(3)))

// ---------------------------------------------------------------------------
// 0. transpose + f32->bf16: dst[c][r] = src[r][c], zero-pad c in [C, Cpad)
// ---------------------------------------------------------------------------
__global__ __launch_bounds__(256) void transpose_bf16_kernel(const float* __restrict__ src,
                                                             __hip_bfloat16* __restrict__ dst,
                                                             int R, int C, int Cpad) {
    __shared__ float t[32][33];
    const int c0 = blockIdx.x * 32, r0 = blockIdx.y * 32;
    const int tx = threadIdx.x & 31, ty = threadIdx.x >> 5;   // 32 x 8
    #pragma unroll
    for (int k = 0; k < 4; k++) {
        const int r = r0 + ty + 8 * k, c = c0 + tx;
        t[ty + 8 * k][tx] = (r < R && c < C) ? src[(size_t)r * C + c] : 0.f;
    }
    __syncthreads();
    #pragma unroll
    for (int k = 0; k < 4; k++) {
        const int c = c0 + ty + 8 * k, r = r0 + tx;
        if (c < Cpad && r < R) dst[(size_t)c * R + r] = __float2bfloat16(t[tx][ty + 8 * k]);
    }
}

// ---------------------------------------------------------------------------
// 1. fused LayerNorm -> bf16
// ---------------------------------------------------------------------------
__global__ __launch_bounds__(256) void ln_bf16_kernel(const float* __restrict__ x,
                                                      const float* __restrict__ g,
                                                      const float* __restrict__ bta,
                                                      __hip_bfloat16* __restrict__ xn) {
    const int row = blockIdx.x;
    const int tid = threadIdx.x;
    const float4 v = ((const float4*)(x + (size_t)row * DM))[tid];
    float s  = v.x + v.y + v.z + v.w;
    float sq = v.x*v.x + v.y*v.y + v.z*v.z + v.w*v.w;
    #pragma unroll
    for (int m = 1; m < 64; m <<= 1) {
        s  += __shfl_xor(s, m);
        sq += __shfl_xor(sq, m);
    }
    __shared__ float ss[4], ssq[4];
    const int w = tid >> 6;
    if ((tid & 63) == 0) { ss[w] = s; ssq[w] = sq; }
    __syncthreads();
    s  = ss[0] + ss[1] + ss[2] + ss[3];
    sq = ssq[0] + ssq[1] + ssq[2] + ssq[3];
    const float mu  = s * (1.f / DM);
    const float var = sq * (1.f / DM) - mu * mu;
    const float rs  = rsqrtf(var + 1e-5f);
    const float4 gv = ((const float4*)g)[tid];
    const float4 bv = ((const float4*)bta)[tid];
    __hip_bfloat16* op = xn + (size_t)row * DM + tid * 4;
    op[0] = __float2bfloat16((v.x - mu) * rs * gv.x + bv.x);
    op[1] = __float2bfloat16((v.y - mu) * rs * gv.y + bv.y);
    op[2] = __float2bfloat16((v.z - mu) * rs * gv.z + bv.z);
    op[3] = __float2bfloat16((v.w - mu) * rs * gv.w + bv.w);
}

// ---------------------------------------------------------------------------
// 2. bf16 MFMA GEMM (m97 structure): 128x128 tile, BK=32, 4 waves, 4x4 MFMA.
// ---------------------------------------------------------------------------
template<int MODE>
__global__ __launch_bounds__(256) void mfma_gemm(const __hip_bfloat16* __restrict__ A,
                                                 const __hip_bfloat16* __restrict__ Bt,
                                                 float* __restrict__ O,
                                                 __hip_bfloat16* __restrict__ Oz,
                                                 const float* __restrict__ Add,
                                                 int K) {
    __shared__ __hip_bfloat16 As[128 * 32];
    __shared__ __hip_bfloat16 Bs[128 * 32];
    const int tid  = threadIdx.x;
    const int lane = tid & 63;
    const int w    = tid >> 6;
    const int row0 = blockIdx.y * 128, col0 = blockIdx.x * 128;
    const int wr0 = (w >> 1) * 64, wc0 = (w & 1) * 64;

    f32x4 acc[4][4];
    #pragma unroll
    for (int i = 0; i < 4; i++)
        #pragma unroll
        for (int j = 0; j < 4; j++) acc[i][j] = f32x4{0.f, 0.f, 0.f, 0.f};

    const int sm = tid >> 2;
    const int sk = (tid & 3) * 8;
    const __hip_bfloat16* gA = A  + (size_t)(row0 + sm) * K + sk;
    const __hip_bfloat16* gB = Bt + (size_t)(col0 + sm) * K + sk;
    __hip_bfloat16* lA = &As[tid * 8];
    __hip_bfloat16* lB = &Bs[tid * 8];
    const size_t g64 = (size_t)64 * K;

    const int fm = lane & 15;
    const int fq = (lane >> 4) * 8;

    for (int k0 = 0; k0 < K; k0 += 32) {
        __builtin_amdgcn_global_load_lds((const AS1 unsigned int*)(gA + k0),
                                         (AS3 unsigned int*)lA, 16, 0, 0);
        __builtin_amdgcn_global_load_lds((const AS1 unsigned int*)(gA + g64 + k0),
                                         (AS3 unsigned int*)(lA + 64 * 32), 16, 0, 0);
        __builtin_amdgcn_global_load_lds((const AS1 unsigned int*)(gB + k0),
                                         (AS3 unsigned int*)lB, 16, 0, 0);
        __builtin_amdgcn_global_load_lds((const AS1 unsigned int*)(gB + g64 + k0),
                                         (AS3 unsigned int*)(lB + 64 * 32), 16, 0, 0);
        __syncthreads();
        bf16x8 af[4], bfr[4];
        #pragma unroll
        for (int i = 0; i < 4; i++)
            af[i] = *(const bf16x8*)&As[(wr0 + i * 16 + fm) * 32 + fq];
        #pragma unroll
        for (int j = 0; j < 4; j++)
            bfr[j] = *(const bf16x8*)&Bs[(wc0 + j * 16 + fm) * 32 + fq];
        #pragma unroll
        for (int i = 0; i < 4; i++)
            #pragma unroll
            for (int j = 0; j < 4; j++)
                acc[i][j] = __builtin_amdgcn_mfma_f32_16x16x32_bf16(af[i], bfr[j], acc[i][j], 0, 0, 0);
        __syncthreads();
    }

    #pragma unroll
    for (int i = 0; i < 4; i++) {
        #pragma unroll
        for (int j = 0; j < 4; j++) {
            #pragma unroll
            for (int r = 0; r < 4; r++) {
                const int row = row0 + wr0 + i * 16 + (lane >> 4) * 4 + r;
                const int col = col0 + wc0 + j * 16 + fm;
                const float v = acc[i][j][r];
                if (MODE == 0) {
                    if (col0 < DI) O[(size_t)row * DI + col] = v;
                    else           Oz[(size_t)row * DI + (col - DI)] = __float2bfloat16(v);
                } else if (MODE == 1) {
                    O[(size_t)row * 128 + col] = v;
                } else {
                    O[(size_t)row * DM + col] = v + Add[(size_t)row * DM + col];
                }
            }
        }
    }
}

// ---------------------------------------------------------------------------
// 3. depthwise causal conv(4) + bias + SiLU.  u f32 [rows][DI] -> uc bf16
// ---------------------------------------------------------------------------
__global__ __launch_bounds__(256) void conv_silu_kernel(const float* __restrict__ u,
                                                        const float* __restrict__ cw,
                                                        const float* __restrict__ cb,
                                                        __hip_bfloat16* __restrict__ uc) {
    const int d  = blockIdx.x * 256 + threadIdx.x;
    const int b  = blockIdx.z;
    const int l0 = blockIdx.y * 16;
    const float w0 = cw[d * 4 + 0], w1 = cw[d * 4 + 1];
    const float w2 = cw[d * 4 + 2], w3 = cw[d * 4 + 3];
    const float bias = cb[d];
    const float* up = u + (size_t)(b * LL) * DI + d;
    float x0 = (l0 - 3 >= 0) ? up[(size_t)(l0 - 3) * DI] : 0.f;
    float x1 = (l0 - 2 >= 0) ? up[(size_t)(l0 - 2) * DI] : 0.f;
    float x2 = (l0 - 1 >= 0) ? up[(size_t)(l0 - 1) * DI] : 0.f;
    __hip_bfloat16* op = uc + (size_t)(b * LL + l0) * DI + d;
    #pragma unroll
    for (int i = 0; i < 16; i++) {
        const float x3 = up[(size_t)(l0 + i) * DI];
        const float v  = bias + w0 * x0 + w1 * x1 + w2 * x2 + w3 * x3;
        const float sig = __builtin_amdgcn_rcpf(1.f + __expf(-v));
        op[(size_t)i * DI] = __float2bfloat16(v * sig);
        x0 = x1; x1 = x2; x2 = x3;
    }
}

// ---------------------------------------------------------------------------
// 5. softplus(dbc[:, :64] @ W_dt + b_dt) -> u buffer (dt storage), stride DI
// ---------------------------------------------------------------------------
__global__ __launch_bounds__(256) void dt_kernel(const float* __restrict__ dbc,
                                                 const float* __restrict__ Wdt,
                                                 const float* __restrict__ bdt,
                                                 float* __restrict__ dtx) {
    __shared__ float ds[16][64];
    const int r0  = blockIdx.y * 16;
    const int tid = threadIdx.x;
    const int c   = blockIdx.x * 256 + tid;
    {
        const int r = tid >> 4, k4 = (tid & 15) * 4;
        *(float4*)&ds[r][k4] = *(const float4*)(dbc + (size_t)(r0 + r) * 128 + k4);
    }
    __syncthreads();
    float acc[16];
    #pragma unroll
    for (int r = 0; r < 16; r++) acc[r] = 0.f;
    #pragma unroll 4
    for (int k = 0; k < 64; k++) {
        const float wv = Wdt[k * DI + c];
        #pragma unroll
        for (int r = 0; r < 16; r++) acc[r] += ds[r][k] * wv;
    }
    const float bb = bdt[c];
    #pragma unroll
    for (int r = 0; r < 16; r++) {
        const float v = acc[r] + bb;
        dtx[(size_t)(r0 + r) * DI + c] = (v > 20.f) ? v : log1pf(__expf(v));
    }
}

// ---------------------------------------------------------------------------
// 6a. scan pass 1 (thread-per-channel): h[16] in registers, B from LDS.
//     P = exp(a_s * sum dt) computed once at chunk end (exact).
// ---------------------------------------------------------------------------
__global__ __launch_bounds__(256) void scan_pass1_kernel(const float* __restrict__ dtb,
                                                         const __hip_bfloat16* __restrict__ uc,
                                                         const float* __restrict__ dbc,
                                                         const float* __restrict__ A_log,
                                                         float* __restrict__ hbuf,
                                                         float* __restrict__ Pbuf) {
    __shared__ float Bsh[CHUNK][16];      // 4 KB
    const int tid = threadIdx.x;
    const int d   = blockIdx.x * 256 + tid;
    const int c   = blockIdx.y;
    const int b   = blockIdx.z;
    const size_t row0 = (size_t)b * LL + (size_t)c * CHUNK;

    // stage B: CHUNK rows x 16 floats = CHUNK*4 float4s (one per thread)
    {
        const int r = tid >> 2, j4 = (tid & 3) * 4;
        *(float4*)&Bsh[r][j4] = *(const float4*)(dbc + (row0 + r) * 128 + DTR + j4);
    }
    float a[DST];
    #pragma unroll
    for (int q = 0; q < 4; q++) {
        const float4 t = *(const float4*)(A_log + (size_t)d * DST + q * 4);
        a[q * 4 + 0] = -__expf(t.x); a[q * 4 + 1] = -__expf(t.y);
        a[q * 4 + 2] = -__expf(t.z); a[q * 4 + 3] = -__expf(t.w);
    }
    __syncthreads();

    const float* dtp = dtb + row0 * DI + d;
    const __hip_bfloat16* ucp = uc + row0 * DI + d;

    float h[DST];
    #pragma unroll
    for (int s = 0; s < DST; s++) h[s] = 0.f;
    float sdt = 0.f;
    float dtv = dtp[0], ucv = __bfloat162float(ucp[0]);
    for (int l = 0; l < CHUNK; l++) {
        const int ln = (l + 1 < CHUNK) ? (l + 1) : l;
        const float dtn = dtp[(size_t)ln * DI];
        const float ucn = __bfloat162float(ucp[(size_t)ln * DI]);
        const float dtu = dtv * ucv;
        sdt += dtv;
        #pragma unroll
        for (int s = 0; s < DST; s++) {
            const float dA = __expf(dtv * a[s]);
            h[s] = fmaf(h[s], dA, dtu * Bsh[l][s]);
        }
        dtv = dtn; ucv = ucn;
    }
    float* hp = hbuf + (((size_t)b * NC + c) * DI + d) * DST;
    float* pp = Pbuf + (((size_t)b * NC + c) * DI + d) * DST;
    #pragma unroll
    for (int q = 0; q < 4; q++) {
        *(float4*)&hp[q * 4] = float4{h[q*4+0], h[q*4+1], h[q*4+2], h[q*4+3]};
        *(float4*)&pp[q * 4] = float4{__expf(sdt * a[q*4+0]), __expf(sdt * a[q*4+1]),
                                      __expf(sdt * a[q*4+2]), __expf(sdt * a[q*4+3])};
    }
}

// ---------------------------------------------------------------------------
// 6b. scan combine: rewrite hbuf[c] := h_in for chunk c
// ---------------------------------------------------------------------------
__global__ __launch_bounds__(256) void scan_combine_kernel(float* __restrict__ hbuf,
                                                           const float* __restrict__ Pbuf) {
    const size_t gid  = (size_t)blockIdx.x * 256 + threadIdx.x;
    const size_t b    = gid >> 15;             // DI*DST = 32768
    const size_t d16s = gid & 32767;
    float H = 0.f;
    #pragma unroll
    for (int c = 0; c < NC; c++) {
        const size_t idx = (b * NC + c) * (DI * DST) + d16s;
        const float hc = hbuf[idx];
        const float Pc = Pbuf[idx];
        hbuf[idx] = H;
        H = hc + Pc * H;
    }
}

// ---------------------------------------------------------------------------
// 6c. scan pass 3 (thread-per-channel): y = sum_s h_s*C_s in registers,
//     + D-skip + SiLU(z) gate; writes gated y bf16 in place over uc.
// ---------------------------------------------------------------------------
__global__ __launch_bounds__(256) void scan_pass3_kernel(const float* __restrict__ dtb,
                                                         __hip_bfloat16* uc,
                                                         const __hip_bfloat16* __restrict__ z,
                                                         const float* __restrict__ dbc,
                                                         const float* __restrict__ A_log,
                                                         const float* __restrict__ Dskip,
                                                         const float* __restrict__ hbuf) {
    __shared__ float BC[CHUNK][32];       // 8 KB: [0:16)=B, [16:32)=C
    const int tid = threadIdx.x;
    const int d   = blockIdx.x * 256 + tid;
    const int c   = blockIdx.y;
    const int b   = blockIdx.z;
    const size_t row0 = (size_t)b * LL + (size_t)c * CHUNK;

    // stage B|C: CHUNK rows x 32 floats = CHUNK*8 float4s (2 per thread)
    #pragma unroll
    for (int i = 0; i < 2; i++) {
        const int idx = i * 256 + tid;
        const int r = idx >> 3, j4 = (idx & 7) * 4;
        *(float4*)&BC[r][j4] = *(const float4*)(dbc + (row0 + r) * 128 + DTR + j4);
    }
    float a[DST];
    #pragma unroll
    for (int q = 0; q < 4; q++) {
        const float4 t = *(const float4*)(A_log + (size_t)d * DST + q * 4);
        a[q * 4 + 0] = -__expf(t.x); a[q * 4 + 1] = -__expf(t.y);
        a[q * 4 + 2] = -__expf(t.z); a[q * 4 + 3] = -__expf(t.w);
    }
    const float dsk = Dskip[d];
    __syncthreads();

    const float* dtp = dtb + row0 * DI + d;
    __hip_bfloat16* ucp = uc + row0 * DI + d;
    const __hip_bfloat16* zp = z + row0 * DI + d;

    float h[DST];
    {
        const float* hp = hbuf + (((size_t)b * NC + c) * DI + d) * DST;
        #pragma unroll
        for (int q = 0; q < 4; q++) {
            const float4 t = *(const float4*)&hp[q * 4];
            h[q*4+0] = t.x; h[q*4+1] = t.y; h[q*4+2] = t.z; h[q*4+3] = t.w;
        }
    }
    float dtv = dtp[0];
    float ucv = __bfloat162float(ucp[0]);
    float zv  = __bfloat162float(zp[0]);
    for (int l = 0; l < CHUNK; l++) {
        const int ln = (l + 1 < CHUNK) ? (l + 1) : l;
        const float dtn = dtp[(size_t)ln * DI];
        const float ucn = __bfloat162float(ucp[(size_t)ln * DI]);
        const float zn  = __bfloat162float(zp[(size_t)ln * DI]);
        const float dtu = dtv * ucv;
        float y = 0.f;
        #pragma unroll
        for (int s = 0; s < DST; s++) {
            const float dA = __expf(dtv * a[s]);
            h[s] = fmaf(h[s], dA, dtu * BC[l][s]);
            y = fmaf(h[s], BC[l][16 + s], y);
        }
        const float yt  = fmaf(ucv, dsk, y);
        const float sig = __builtin_amdgcn_rcpf(1.f + __expf(-zv));
        ucp[(size_t)l * DI] = __float2bfloat16(yt * (zv * sig));
        dtv = dtn; ucv = ucn; zv = zn;
    }
}

// ---------------------------------------------------------------------------
extern "C" void kernel_launch(void* const* d_in, const int* in_sizes, int n_in,
                              void* d_out, int out_size, void* d_ws, size_t ws_size,
                              hipStream_t stream) {
    const float* x      = (const float*)d_in[0];
    const float* ln_g   = (const float*)d_in[1];
    const float* ln_b   = (const float*)d_in[2];
    const float* W_in   = (const float*)d_in[3];
    const float* conv_w = (const float*)d_in[4];
    const float* conv_b = (const float*)d_in[5];
    const float* W_x    = (const float*)d_in[6];
    const float* W_dt   = (const float*)d_in[7];
    const float* b_dt   = (const float*)d_in[8];
    const float* A_log  = (const float*)d_in[9];
    const float* Dskip  = (const float*)d_in[10];
    const float* W_out  = (const float*)d_in[11];
    float* out = (float*)d_out;

    // workspace layout (bytes), total 193 MB (proven budget: 195 MB)
    const size_t MB = 1024ull * 1024ull;
    char* wsb = (char*)d_ws;
    float*          u     = (float*)(wsb);                     // 64 MB: u -> dt
    __hip_bfloat16* z     = (__hip_bfloat16*)(wsb + 64 * MB);  // 32 MB
    __hip_bfloat16* uc    = (__hip_bfloat16*)(wsb + 96 * MB);  // 32 MB: uc -> yg
    __hip_bfloat16* xn    = (__hip_bfloat16*)(wsb + 128 * MB); // 16 MB
    __hip_bfloat16* WinT  = (__hip_bfloat16*)(wsb + 144 * MB); // 8 MB
    __hip_bfloat16* WoutT = (__hip_bfloat16*)(wsb + 152 * MB); // 4 MB
    __hip_bfloat16* WxT   = (__hip_bfloat16*)(wsb + 156 * MB); // 0.5 MB
    float*          dbc   = (float*)(wsb + 157 * MB);          // 4 MB [8192][128]
    float*          hbuf  = (float*)(wsb + 161 * MB);          // 16 MB: B*NC*DI*DST
    float*          Pbuf  = (float*)(wsb + 177 * MB);          // 16 MB

    transpose_bf16_kernel<<<dim3(128, 32), 256, 0, stream>>>(W_in, WinT, DM, 2 * DI, 2 * DI);
    transpose_bf16_kernel<<<dim3(32, 64), 256, 0, stream>>>(W_out, WoutT, DI, DM, DM);
    transpose_bf16_kernel<<<dim3(4, 64), 256, 0, stream>>>(W_x, WxT, DI, 96, 128);
    ln_bf16_kernel<<<ROWS, 256, 0, stream>>>(x, ln_g, ln_b, xn);
    mfma_gemm<0><<<dim3(32, 64), 256, 0, stream>>>(xn, WinT, u, z, nullptr, DM);
    conv_silu_kernel<<<dim3(DI / 256, LL / 16, BB), 256, 0, stream>>>(u, conv_w, conv_b, uc);
    mfma_gemm<1><<<dim3(1, 64), 256, 0, stream>>>(uc, WxT, dbc, nullptr, nullptr, DI);
    dt_kernel<<<dim3(DI / 256, ROWS / 16), 256, 0, stream>>>(dbc, W_dt, b_dt, u);
    scan_pass1_kernel<<<dim3(DI / 256, NC, BB), 256, 0, stream>>>(u, uc, dbc, A_log, hbuf, Pbuf);
    scan_combine_kernel<<<(BB * DI * DST) / 256, 256, 0, stream>>>(hbuf, Pbuf);
    scan_pass3_kernel<<<dim3(DI / 256, NC, BB), 256, 0, stream>>>(u, uc, z, dbc, A_log, Dskip, hbuf);
    mfma_gemm<2><<<dim3(DM / 128, ROWS / 128), 256, 0, stream>>>(uc, WoutT, out, nullptr, x, DI);
}